// Round 9
// baseline (557.743 us; speedup 1.0000x reference)
//
#include <hip/hip_runtime.h>
#include <hip/hip_cooperative_groups.h>

namespace cg = cooperative_groups;

#define N_NODES 75000
#define N_EDGES 1200000
#define DIM 64
#define NCOPY 8
#define CNT_STRIDE 75008                       // N_NODES padded to 16B multiple
#define NCHUNK 74                              // ceil(N_NODES/1024)
#define SCAN_BLK 1024
#define N_SCAN_BLKS NCHUNK
#define HIST_BLKS ((N_EDGES + 1023) / 1024)

typedef _Float16 half8 __attribute__((ext_vector_type(8)));  // 16B = 8 halfs

// Broadcast lane l (wave-uniform) of v to all lanes via v_readlane (VALU).
__device__ __forceinline__ float lane_bcf(float v, int l) {
    return __int_as_float(__builtin_amdgcn_readlane(__float_as_int(v), l));
}
__device__ __forceinline__ int lane_bci(int v, int l) {
    return __builtin_amdgcn_readlane(v, l);
}

// ===========================================================================
// MEGA KERNEL (cooperative, single dispatch).
// R8 evidence: kernel-sum ~171us vs total 261.8us -> ~90us of inter-dispatch
// gap overhead, the largest single cost in the pipeline. One cooperative
// launch with grid.sync() phase barriers removes it. Phase bodies are the
// R8 kernels unchanged (grid-strided). hist's ~50us is a memory-side atomic
// rate floor (R2-R7: invariant under privatization/scope/XCC/fusion) — left
// as is; node_wave placed BEFORE hist in the same phase (independent, no
// internal barrier) so block-level skew smooths the tail.
// ===========================================================================
__global__ __launch_bounds__(256, 4) void mega_kernel(
    const int* __restrict__ src, const int* __restrict__ dst,
    const float* __restrict__ d_u, const float* __restrict__ p_u,
    const float* __restrict__ w_v, const float* __restrict__ w_q,
    const float* __restrict__ w_k,
    const float* __restrict__ e1, const float* __restrict__ e2,
    double* __restrict__ h_src, double* __restrict__ h_dst,
    _Float16* __restrict__ wvh,
    int* __restrict__ cnt, int* __restrict__ row,
    int* __restrict__ cnt8, unsigned int* __restrict__ pub,
    int* __restrict__ rank, int* __restrict__ csr_src,
    float* __restrict__ out)
{
    cg::grid_group grid = cg::this_grid();
    const int gtid = blockIdx.x * 256 + threadIdx.x;
    const int gstride = gridDim.x * 256;
    const int lane = threadIdx.x & 63;

    // ---- P0: zero cnt8 + pub (replaces hipMemsetAsync dispatch) ----
    for (int i = gtid; i < NCOPY * CNT_STRIDE; i += gstride) cnt8[i] = 0;
    if (gtid < 128) pub[gtid] = 0u;
    grid.sync();

    // ---- P1a: node_wave (one wave per node, grid-strided) ----
    {
        __shared__ double al_sh[DIM];
        __shared__ double bl_sh[DIM];
        if (threadIdx.x < DIM) {
            double al = 0.0, bl = 0.0;
            #pragma unroll 8
            for (int j = 0; j < DIM; ++j) {
                al += (double)e1[j] * (double)w_k[j * DIM + threadIdx.x];
                bl += (double)e2[j] * (double)w_q[j * DIM + threadIdx.x];
            }
            al_sh[threadIdx.x] = al;
            bl_sh[threadIdx.x] = bl;
        }
        float w[DIM];
        const float4* wr = (const float4*)(w_v + (size_t)lane * DIM);
        #pragma unroll
        for (int k = 0; k < DIM / 4; ++k) {
            float4 v = wr[k];
            w[4 * k + 0] = v.x; w[4 * k + 1] = v.y;
            w[4 * k + 2] = v.z; w[4 * k + 3] = v.w;
        }
        __syncthreads();
        double al = al_sh[lane];
        double bl = bl_sh[lane];

        int wid = gtid >> 6;
        int nw = gstride >> 6;
        for (int i = wid; i < N_NODES; i += nw) {
            float pl = p_u[(size_t)i * DIM + lane];
            float dl = d_u[(size_t)i * DIM + lane];

            double hs = (double)pl * al;
            #pragma unroll
            for (int off = 32; off > 0; off >>= 1) hs += __shfl_xor(hs, off, 64);
            double hd = (double)dl * bl;
            #pragma unroll
            for (int off = 32; off > 0; off >>= 1) hd += __shfl_xor(hd, off, 64);
            if (lane == 0) { h_src[i] = hs; h_dst[i] = hd; }

            float a0 = 0.f, a1 = 0.f, a2 = 0.f, a3 = 0.f;
            #pragma unroll
            for (int d = 0; d < DIM; d += 4) {
                a0 += w[d + 0] * lane_bcf(pl, d + 0);
                a1 += w[d + 1] * lane_bcf(pl, d + 1);
                a2 += w[d + 2] * lane_bcf(pl, d + 2);
                a3 += w[d + 3] * lane_bcf(pl, d + 3);
            }
            wvh[(size_t)i * DIM + lane] = (_Float16)((a0 + a1) + (a2 + a3));
        }
    }
    // ---- P1b: hist (independent of P1a; no barrier between) ----
    {
        int xcc;
        asm volatile("s_getreg_b32 %0, hwreg(HW_REG_XCC_ID)" : "=s"(xcc));
        xcc &= (NCOPY - 1);
        int* mycnt = cnt8 + (size_t)xcc * CNT_STRIDE;
        int tag = xcc << 28;
        for (int e = gtid; e < N_EDGES; e += gstride) {
            int r = atomicAdd(&mycnt[dst[e]], 1);
            rank[e] = r | tag;
        }
    }
    grid.sync();

    // ---- P2: CSR scan, 74 blocks, publish/spin lookback (R5-proven) ----
    if (blockIdx.x < NCHUNK) {
        __shared__ int sh[256];
        __shared__ int bpref;
        int t = threadIdx.x;
        int i0 = (blockIdx.x << 10) + 4 * t;
        int deg[4], loc[4];
        int th_sum = 0;
        #pragma unroll
        for (int k = 0; k < 4; ++k) {
            int i = i0 + k;
            int run = 0;
            if (i < N_NODES) {
                #pragma unroll
                for (int c = 0; c < NCOPY; ++c) {
                    int x = cnt8[(size_t)c * CNT_STRIDE + i];
                    cnt8[(size_t)c * CNT_STRIDE + i] = run;   // P[c][i]
                    run += x;
                }
                cnt[i] = run;                                  // degree
            }
            deg[k] = run;
            loc[k] = th_sum;
            th_sum += run;
        }
        sh[t] = th_sum;
        __syncthreads();
        for (int off = 1; off < 256; off <<= 1) {
            int tt = (t >= off) ? sh[t - off] : 0;
            __syncthreads();
            sh[t] += tt;
            __syncthreads();
        }
        int th_excl = sh[t] - th_sum;
        if (t == 255)
            atomicExch(&pub[blockIdx.x], (unsigned)sh[255] | 0x80000000u);
        if (t < 64) {
            int s = 0;
            for (int l = t; l < (int)blockIdx.x; l += 64) {
                unsigned x;
                do { x = atomicAdd(&pub[l], 0u); } while (!(x & 0x80000000u));
                s += (int)(x & 0x7FFFFFFFu);
            }
            #pragma unroll
            for (int off = 32; off > 0; off >>= 1) s += __shfl_xor(s, off, 64);
            if (t == 0) bpref = s;
        }
        __syncthreads();
        #pragma unroll
        for (int k = 0; k < 4; ++k) {
            int i = i0 + k;
            if (i < N_NODES) row[i] = bpref + th_excl + loc[k];
        }
        (void)deg;
    }
    grid.sync();

    // ---- P3: build (atomic-free scatter; nt store dodges RFO) ----
    for (int e = gtid; e < N_EDGES; e += gstride) {
        int d = dst[e];
        int rp = rank[e];
        int copy = (rp >> 28) & (NCOPY - 1);
        int r = rp & 0x0FFFFFFF;
        int pos = row[d] + cnt8[(size_t)copy * CNT_STRIDE + d] + r;
        __builtin_nontemporal_store(src[e], &csr_src[pos]);
    }
    grid.sync();

    // ---- P4: gather (one wave per node; f16 rows, 8 edges/wave-load) ----
    {
        int wid = gtid >> 6;
        int nw = gstride >> 6;
        for (int node = wid; node < N_NODES; node += nw) {
            int start = row[node];
            int deg = cnt[node];
            double hd = h_dst[node];

            if (deg <= 64) {
                int s0 = 0;
                double c0 = 0.0;
                if (lane < deg) {
                    s0 = csr_src[start + lane];
                    c0 = h_src[s0] + hd;
                }
                double r = c0;
                if (deg > 32) r += __shfl_xor(r, 32, 64);
                if (deg > 16) r += __shfl_xor(r, 16, 64);
                r += __shfl_xor(r, 8, 64);
                r += __shfl_xor(r, 4, 64);
                r += __shfl_xor(r, 2, 64);
                r += __shfl_xor(r, 1, 64);
                double inv = 1.0 / r;
                float cf0 = (lane < deg) ? (float)(c0 * inv) : 0.f;

                int g8 = lane >> 3;
                int sub8 = lane & 7;
                float ac[8];
                #pragma unroll
                for (int k = 0; k < 8; ++k) ac[k] = 0.f;

                int rounds = (deg + 7) >> 3;
                int j = 0;
                for (; j + 2 <= rounds; j += 2) {
                    int l0 = 8 * j + g8;
                    int l1 = l0 + 8;
                    int   sA = __shfl(s0, l0, 64);
                    float cA = __shfl(cf0, l0, 64);
                    int   sB = __shfl(s0, l1, 64);
                    float cB = __shfl(cf0, l1, 64);
                    half8 vA = ((const half8*)(wvh + (size_t)sA * DIM))[sub8];
                    half8 vB = ((const half8*)(wvh + (size_t)sB * DIM))[sub8];
                    #pragma unroll
                    for (int k = 0; k < 8; ++k) ac[k] += (float)vA[k] * cA;
                    #pragma unroll
                    for (int k = 0; k < 8; ++k) ac[k] += (float)vB[k] * cB;
                }
                if (j < rounds) {
                    int l0 = 8 * j + g8;
                    int   sA = __shfl(s0, l0, 64);
                    float cA = __shfl(cf0, l0, 64);
                    half8 vA = ((const half8*)(wvh + (size_t)sA * DIM))[sub8];
                    #pragma unroll
                    for (int k = 0; k < 8; ++k) ac[k] += (float)vA[k] * cA;
                }
                #pragma unroll
                for (int off = 8; off < 64; off <<= 1) {
                    #pragma unroll
                    for (int k = 0; k < 8; ++k) ac[k] += __shfl_xor(ac[k], off, 64);
                }
                if (g8 == 0) {
                    float4* orow = (float4*)(out + (size_t)node * DIM + sub8 * 8);
                    float4 o0; o0.x = ac[0]; o0.y = ac[1]; o0.z = ac[2]; o0.w = ac[3];
                    float4 o1; o1.x = ac[4]; o1.y = ac[5]; o1.z = ac[6]; o1.w = ac[7];
                    orow[0] = o0; orow[1] = o1;
                }
            } else {
                double denom = 0.0;
                for (int base = 0; base < deg; base += 64) {
                    int m = deg - base; if (m > 64) m = 64;
                    double c = 0.0;
                    if (lane < m) {
                        int s = csr_src[start + base + lane];
                        c = h_src[s] + hd;
                    }
                    #pragma unroll
                    for (int off = 32; off > 0; off >>= 1) c += __shfl_xor(c, off, 64);
                    denom += c;
                }
                double inv = 1.0 / denom;
                float acc = 0.f;
                for (int base = 0; base < deg; base += 64) {
                    int m = deg - base; if (m > 64) m = 64;
                    int s1 = 0; float cf1 = 0.f;
                    if (lane < m) {
                        s1 = csr_src[start + base + lane];
                        cf1 = (float)((h_src[s1] + hd) * inv);
                    }
                    for (int j = 0; j < m; ++j) {
                        int s = lane_bci(s1, j);
                        float cf = lane_bcf(cf1, j);
                        acc += (float)wvh[(size_t)s * DIM + lane] * cf;
                    }
                }
                out[(size_t)node * DIM + lane] = acc;
            }
        }
    }
}

// ===========================================================================
// Fallback path (R8 kernels, CNT_STRIDE-adjusted) — used only if the
// cooperative launch is rejected at enqueue time.
// ===========================================================================
__global__ __launch_bounds__(256) void hist_kernel(
    const int* __restrict__ dst, int* __restrict__ cnt8,
    int* __restrict__ rank) {
    int xcc;
    asm volatile("s_getreg_b32 %0, hwreg(HW_REG_XCC_ID)" : "=s"(xcc));
    xcc &= (NCOPY - 1);
    int* mycnt = cnt8 + (size_t)xcc * CNT_STRIDE;
    int tag = xcc << 28;
    int base = blockIdx.x << 10;
    #pragma unroll
    for (int k = 0; k < 4; ++k) {
        int e = base + k * 256 + threadIdx.x;
        if (e < N_EDGES) {
            int r = atomicAdd(&mycnt[dst[e]], 1);
            rank[e] = r | tag;
        }
    }
}

__global__ __launch_bounds__(256, 4) void node_wave(
    const float* __restrict__ d_u, const float* __restrict__ p_u,
    const float* __restrict__ w_v, const float* __restrict__ w_q,
    const float* __restrict__ w_k,
    const float* __restrict__ e1, const float* __restrict__ e2,
    double* __restrict__ h_src, double* __restrict__ h_dst,
    _Float16* __restrict__ wvh) {
    __shared__ double al_sh[DIM];
    __shared__ double bl_sh[DIM];
    int lane = threadIdx.x & 63;
    if (threadIdx.x < DIM) {
        double al = 0.0, bl = 0.0;
        #pragma unroll 8
        for (int j = 0; j < DIM; ++j) {
            al += (double)e1[j] * (double)w_k[j * DIM + threadIdx.x];
            bl += (double)e2[j] * (double)w_q[j * DIM + threadIdx.x];
        }
        al_sh[threadIdx.x] = al;
        bl_sh[threadIdx.x] = bl;
    }
    float w[DIM];
    const float4* wr = (const float4*)(w_v + (size_t)lane * DIM);
    #pragma unroll
    for (int k = 0; k < DIM / 4; ++k) {
        float4 v = wr[k];
        w[4 * k + 0] = v.x; w[4 * k + 1] = v.y;
        w[4 * k + 2] = v.z; w[4 * k + 3] = v.w;
    }
    __syncthreads();
    double al = al_sh[lane];
    double bl = bl_sh[lane];
    int wave = (blockIdx.x * 256 + threadIdx.x) >> 6;
    int nwaves = gridDim.x * 4;
    for (int i = wave; i < N_NODES; i += nwaves) {
        float pl = p_u[(size_t)i * DIM + lane];
        float dl = d_u[(size_t)i * DIM + lane];
        double hs = (double)pl * al;
        #pragma unroll
        for (int off = 32; off > 0; off >>= 1) hs += __shfl_xor(hs, off, 64);
        double hd = (double)dl * bl;
        #pragma unroll
        for (int off = 32; off > 0; off >>= 1) hd += __shfl_xor(hd, off, 64);
        if (lane == 0) { h_src[i] = hs; h_dst[i] = hd; }
        float a0 = 0.f, a1 = 0.f, a2 = 0.f, a3 = 0.f;
        #pragma unroll
        for (int d = 0; d < DIM; d += 4) {
            a0 += w[d + 0] * lane_bcf(pl, d + 0);
            a1 += w[d + 1] * lane_bcf(pl, d + 1);
            a2 += w[d + 2] * lane_bcf(pl, d + 2);
            a3 += w[d + 3] * lane_bcf(pl, d + 3);
        }
        wvh[(size_t)i * DIM + lane] = (_Float16)((a0 + a1) + (a2 + a3));
    }
}

__global__ __launch_bounds__(SCAN_BLK) void scan_kernel(
    int* __restrict__ cnt8, int* __restrict__ cnt,
    int* __restrict__ row, unsigned int* __restrict__ pub) {
    __shared__ int sh[SCAN_BLK];
    __shared__ int bpref;
    int tid = threadIdx.x;
    int i = blockIdx.x * SCAN_BLK + tid;
    int v = 0;
    if (i < N_NODES) {
        int run = 0;
        #pragma unroll
        for (int c = 0; c < NCOPY; ++c) {
            int x = cnt8[(size_t)c * CNT_STRIDE + i];
            cnt8[(size_t)c * CNT_STRIDE + i] = run;
            run += x;
        }
        v = run;
        cnt[i] = run;
    }
    sh[tid] = v;
    __syncthreads();
    for (int off = 1; off < SCAN_BLK; off <<= 1) {
        int t = (tid >= off) ? sh[tid - off] : 0;
        __syncthreads();
        sh[tid] += t;
        __syncthreads();
    }
    int incl = sh[tid];
    if (tid == SCAN_BLK - 1)
        atomicExch(&pub[blockIdx.x], (unsigned)incl | 0x80000000u);
    if (tid < 64) {
        int s = 0;
        for (int l = tid; l < (int)blockIdx.x; l += 64) {
            unsigned x;
            do { x = atomicAdd(&pub[l], 0u); } while (!(x & 0x80000000u));
            s += (int)(x & 0x7FFFFFFFu);
        }
        #pragma unroll
        for (int off = 32; off > 0; off >>= 1) s += __shfl_xor(s, off, 64);
        if (tid == 0) bpref = s;
    }
    __syncthreads();
    if (i < N_NODES) row[i] = bpref + incl - v;
}

__global__ __launch_bounds__(256) void build_kernel(
    const int* __restrict__ src, const int* __restrict__ dst,
    const int* __restrict__ row, const int* __restrict__ cnt8,
    const int* __restrict__ rank, int* __restrict__ csr_src) {
    int e = blockIdx.x * 256 + threadIdx.x;
    if (e >= N_EDGES) return;
    int d = dst[e];
    int rp = rank[e];
    int copy = (rp >> 28) & (NCOPY - 1);
    int r = rp & 0x0FFFFFFF;
    int pos = row[d] + cnt8[(size_t)copy * CNT_STRIDE + d] + r;
    __builtin_nontemporal_store(src[e], &csr_src[pos]);
}

__global__ __launch_bounds__(256) void node_gather(
    const int* __restrict__ row, const int* __restrict__ cnt,
    const int* __restrict__ csr_src,
    const double* __restrict__ h_src, const double* __restrict__ h_dst,
    const _Float16* __restrict__ wvh, float* __restrict__ out) {
    int gtid = blockIdx.x * 256 + threadIdx.x;
    int node = gtid >> 6;
    int lane = threadIdx.x & 63;
    if (node >= N_NODES) return;
    int start = row[node];
    int deg = cnt[node];
    double hd = h_dst[node];
    if (deg <= 64) {
        int s0 = 0;
        double c0 = 0.0;
        if (lane < deg) {
            s0 = csr_src[start + lane];
            c0 = h_src[s0] + hd;
        }
        double r = c0;
        if (deg > 32) r += __shfl_xor(r, 32, 64);
        if (deg > 16) r += __shfl_xor(r, 16, 64);
        r += __shfl_xor(r, 8, 64);
        r += __shfl_xor(r, 4, 64);
        r += __shfl_xor(r, 2, 64);
        r += __shfl_xor(r, 1, 64);
        double inv = 1.0 / r;
        float cf0 = (lane < deg) ? (float)(c0 * inv) : 0.f;
        int g8 = lane >> 3;
        int sub8 = lane & 7;
        float ac[8];
        #pragma unroll
        for (int k = 0; k < 8; ++k) ac[k] = 0.f;
        int rounds = (deg + 7) >> 3;
        int j = 0;
        for (; j + 2 <= rounds; j += 2) {
            int l0 = 8 * j + g8;
            int l1 = l0 + 8;
            int   sA = __shfl(s0, l0, 64);
            float cA = __shfl(cf0, l0, 64);
            int   sB = __shfl(s0, l1, 64);
            float cB = __shfl(cf0, l1, 64);
            half8 vA = ((const half8*)(wvh + (size_t)sA * DIM))[sub8];
            half8 vB = ((const half8*)(wvh + (size_t)sB * DIM))[sub8];
            #pragma unroll
            for (int k = 0; k < 8; ++k) ac[k] += (float)vA[k] * cA;
            #pragma unroll
            for (int k = 0; k < 8; ++k) ac[k] += (float)vB[k] * cB;
        }
        if (j < rounds) {
            int l0 = 8 * j + g8;
            int   sA = __shfl(s0, l0, 64);
            float cA = __shfl(cf0, l0, 64);
            half8 vA = ((const half8*)(wvh + (size_t)sA * DIM))[sub8];
            #pragma unroll
            for (int k = 0; k < 8; ++k) ac[k] += (float)vA[k] * cA;
        }
        #pragma unroll
        for (int off = 8; off < 64; off <<= 1) {
            #pragma unroll
            for (int k = 0; k < 8; ++k) ac[k] += __shfl_xor(ac[k], off, 64);
        }
        if (g8 == 0) {
            float4* orow = (float4*)(out + (size_t)node * DIM + sub8 * 8);
            float4 o0; o0.x = ac[0]; o0.y = ac[1]; o0.z = ac[2]; o0.w = ac[3];
            float4 o1; o1.x = ac[4]; o1.y = ac[5]; o1.z = ac[6]; o1.w = ac[7];
            orow[0] = o0; orow[1] = o1;
        }
    } else {
        double denom = 0.0;
        for (int base = 0; base < deg; base += 64) {
            int m = deg - base; if (m > 64) m = 64;
            double c = 0.0;
            if (lane < m) {
                int s = csr_src[start + base + lane];
                c = h_src[s] + hd;
            }
            #pragma unroll
            for (int off = 32; off > 0; off >>= 1) c += __shfl_xor(c, off, 64);
            denom += c;
        }
        double inv = 1.0 / denom;
        float acc = 0.f;
        for (int base = 0; base < deg; base += 64) {
            int m = deg - base; if (m > 64) m = 64;
            int s1 = 0; float cf1 = 0.f;
            if (lane < m) {
                s1 = csr_src[start + base + lane];
                cf1 = (float)((h_src[s1] + hd) * inv);
            }
            for (int j = 0; j < m; ++j) {
                int s = lane_bci(s1, j);
                float cf = lane_bcf(cf1, j);
                acc += (float)wvh[(size_t)s * DIM + lane] * cf;
            }
        }
        out[(size_t)node * DIM + lane] = acc;
    }
}

// ---------------------------------------------------------------------------
// Launch: ONE cooperative dispatch (fallback: R8 multi-launch).
// ---------------------------------------------------------------------------
extern "C" void kernel_launch(void* const* d_in, const int* in_sizes, int n_in,
                              void* d_out, int out_size, void* d_ws, size_t ws_size,
                              hipStream_t stream) {
    const float* d_u = (const float*)d_in[0];
    const float* p_u = (const float*)d_in[1];
    const float* w_q = (const float*)d_in[2];
    const float* w_k = (const float*)d_in[3];
    const float* w_v = (const float*)d_in[4];
    const float* e1  = (const float*)d_in[5];
    const float* e2  = (const float*)d_in[6];
    const int*   src = (const int*)d_in[7];
    const int*   dst = (const int*)d_in[8];
    float* out = (float*)d_out;

    // Workspace: doubles first (8B aligned), then halfs, then ints.
    double* h_src  = (double*)d_ws;
    double* h_dst  = h_src + N_NODES;
    _Float16* wvh  = (_Float16*)(h_dst + N_NODES);    // N_NODES*DIM halfs
    int*    cnt    = (int*)(wvh + (size_t)N_NODES * DIM);
    int*    row    = cnt + N_NODES;
    int*    cnt8   = row + N_NODES;                   // NCOPY*CNT_STRIDE ints
    unsigned int* pub = (unsigned int*)(cnt8 + (size_t)NCOPY * CNT_STRIDE);
    int*    rank   = (int*)pub + 128;                 // N_EDGES ints
    int*    csr_src= rank + N_EDGES;                  // N_EDGES ints

    // Grid: all blocks co-resident. launch_bounds(256,4) -> >=4 blocks/CU.
    int maxb = 4;
    (void)hipOccupancyMaxActiveBlocksPerMultiprocessor(&maxb, mega_kernel,
                                                       256, 0);
    if (maxb < 1) maxb = 1;
    long nblk = (long)maxb * 256;
    if (nblk > 2048) nblk = 2048;
    if (nblk < 256) nblk = 256;                       // >= NCHUNK

    void* kargs[] = {
        (void*)&src, (void*)&dst,
        (void*)&d_u, (void*)&p_u, (void*)&w_v, (void*)&w_q, (void*)&w_k,
        (void*)&e1, (void*)&e2,
        (void*)&h_src, (void*)&h_dst, (void*)&wvh,
        (void*)&cnt, (void*)&row, (void*)&cnt8, (void*)&pub,
        (void*)&rank, (void*)&csr_src, (void*)&out
    };

    hipError_t err = hipLaunchCooperativeKernel(
        (const void*)mega_kernel, dim3((unsigned)nblk), dim3(256),
        kargs, 0, stream);

    if (err != hipSuccess) {
        // Fallback: R8 multi-launch path.
        hipMemsetAsync(cnt8, 0,
                       sizeof(int) * ((size_t)NCOPY * CNT_STRIDE + 128),
                       stream);
        hist_kernel<<<HIST_BLKS, 256, 0, stream>>>(dst, cnt8, rank);
        node_wave<<<1024, 256, 0, stream>>>(
            d_u, p_u, w_v, w_q, w_k, e1, e2, h_src, h_dst, wvh);
        scan_kernel<<<N_SCAN_BLKS, SCAN_BLK, 0, stream>>>(cnt8, cnt, row, pub);
        build_kernel<<<(N_EDGES + 255) / 256, 256, 0, stream>>>(
            src, dst, row, cnt8, rank, csr_src);
        node_gather<<<(N_NODES * 64 + 255) / 256, 256, 0, stream>>>(
            row, cnt, csr_src, h_src, h_dst, wvh, out);
    }
}

// Round 10
// 225.651 us; speedup vs baseline: 2.4717x; 2.4717x over previous
//
#include <hip/hip_runtime.h>

#define N_NODES 75000
#define N_EDGES 1200000
#define DIM 64

#define EPB 4096                        // edges per hist/scatter block
#define NEB ((N_EDGES + EPB - 1) / EPB) // 293 edge-blocks
#define BKT_SHIFT 7
#define NPB 128                         // nodes per bucket (1<<7)
#define NBKT ((N_NODES + NPB - 1) / NPB) // 586 buckets
#define NCTR (NBKT * NEB)               // 171698 counters
#define NSB ((NCTR + 1023) / 1024)      // 168 scan blocks
#define NW_BLKS 1024                    // node_wave blocks inside fat
#define CSR_CAP 3072                    // max edges/bucket (mean 2048, +22 sigma)

typedef _Float16 half8 __attribute__((ext_vector_type(8)));  // 16B = 8 halfs

// Broadcast lane l (wave-uniform) of v to all lanes via v_readlane (VALU).
__device__ __forceinline__ float lane_bcf(float v, int l) {
    return __int_as_float(__builtin_amdgcn_readlane(__float_as_int(v), l));
}
__device__ __forceinline__ int lane_bci(int v, int l) {
    return __builtin_amdgcn_readlane(v, l);
}

// ===========================================================================
// Dispatch 1 — FAT: bucket-histogram (blocks 0..NEB-1) + node_wave (rest).
// R9 post-mortem: grid.sync = L2 flush per sync (+50MB writes, +70MB fetch,
// ~100us each) -> cooperative path abandoned. Instead the 1.2M GLOBAL
// atomics (24 G/s fabric floor, R2-R7) are replaced by LDS atomics over
// 586 coarse buckets (dst>>7): per-block LDS histogram -> per-(bucket,block)
// counter store. No memset needed (counters stored, not accumulated).
// Sequential roles (R3: time==sum, no loss) save one dispatch gap.
// ===========================================================================
__global__ __launch_bounds__(256, 4) void fat_kernel(
    const int* __restrict__ dst,
    const float* __restrict__ d_u, const float* __restrict__ p_u,
    const float* __restrict__ w_v, const float* __restrict__ w_q,
    const float* __restrict__ w_k,
    const float* __restrict__ e1, const float* __restrict__ e2,
    double* __restrict__ h_src, double* __restrict__ h_dst,
    _Float16* __restrict__ wvh,
    int* __restrict__ counters, unsigned int* __restrict__ pub) {

    if (blockIdx.x < NEB) {
        // ---- bucket histogram: 4096 edges -> 586 LDS bins ----
        __shared__ int lbin[NBKT];
        for (int b = threadIdx.x; b < NBKT; b += 256) lbin[b] = 0;
        if (blockIdx.x == 0) pub[threadIdx.x] = 0u;   // 256 >= NSB entries
        __syncthreads();
        int base = blockIdx.x * EPB;
        #pragma unroll
        for (int k = 0; k < EPB / 256; ++k) {
            int e = base + k * 256 + threadIdx.x;
            if (e < N_EDGES) atomicAdd(&lbin[dst[e] >> BKT_SHIFT], 1);
        }
        __syncthreads();
        for (int b = threadIdx.x; b < NBKT; b += 256)
            counters[(size_t)b * NEB + blockIdx.x] = lbin[b];
        return;
    }

    // ---- node_wave: one wave per node, grid-strided (R8 body, f16 out) ----
    __shared__ double al_sh[DIM];
    __shared__ double bl_sh[DIM];
    int lane = threadIdx.x & 63;
    if (threadIdx.x < DIM) {
        double al = 0.0, bl = 0.0;
        #pragma unroll 8
        for (int j = 0; j < DIM; ++j) {
            al += (double)e1[j] * (double)w_k[j * DIM + threadIdx.x];
            bl += (double)e2[j] * (double)w_q[j * DIM + threadIdx.x];
        }
        al_sh[threadIdx.x] = al;
        bl_sh[threadIdx.x] = bl;
    }
    float w[DIM];
    const float4* wr = (const float4*)(w_v + (size_t)lane * DIM);
    #pragma unroll
    for (int k = 0; k < DIM / 4; ++k) {
        float4 v = wr[k];
        w[4 * k + 0] = v.x; w[4 * k + 1] = v.y;
        w[4 * k + 2] = v.z; w[4 * k + 3] = v.w;
    }
    __syncthreads();
    double al = al_sh[lane];
    double bl = bl_sh[lane];

    int wid = ((blockIdx.x - NEB) * 256 + threadIdx.x) >> 6;
    int nw = NW_BLKS * 4;
    for (int i = wid; i < N_NODES; i += nw) {
        float pl = p_u[(size_t)i * DIM + lane];
        float dl = d_u[(size_t)i * DIM + lane];
        double hs = (double)pl * al;
        #pragma unroll
        for (int off = 32; off > 0; off >>= 1) hs += __shfl_xor(hs, off, 64);
        double hd = (double)dl * bl;
        #pragma unroll
        for (int off = 32; off > 0; off >>= 1) hd += __shfl_xor(hd, off, 64);
        if (lane == 0) { h_src[i] = hs; h_dst[i] = hd; }
        float a0 = 0.f, a1 = 0.f, a2 = 0.f, a3 = 0.f;
        #pragma unroll
        for (int d = 0; d < DIM; d += 4) {
            a0 += w[d + 0] * lane_bcf(pl, d + 0);
            a1 += w[d + 1] * lane_bcf(pl, d + 1);
            a2 += w[d + 2] * lane_bcf(pl, d + 2);
            a3 += w[d + 3] * lane_bcf(pl, d + 3);
        }
        wvh[(size_t)i * DIM + lane] = (_Float16)((a0 + a1) + (a2 + a3));
    }
}

// ===========================================================================
// Dispatch 2 — exclusive scan of counters (bucket-major), in place.
// Lookback publish/spin (R5-proven; 168 blocks all co-resident).
// After this, counters[b*NEB+eb] = global base of (bucket b, edge-block eb),
// and counters[b*NEB] = start of bucket b in the sorted pairs array.
// ===========================================================================
__global__ __launch_bounds__(1024) void scan_kernel(
    int* __restrict__ c, unsigned int* __restrict__ pub) {
    __shared__ int sh[1024];
    __shared__ int bpref;
    int tid = threadIdx.x;
    int i = blockIdx.x * 1024 + tid;
    int v = (i < NCTR) ? c[i] : 0;
    sh[tid] = v;
    __syncthreads();
    for (int off = 1; off < 1024; off <<= 1) {
        int t = (tid >= off) ? sh[tid - off] : 0;
        __syncthreads();
        sh[tid] += t;
        __syncthreads();
    }
    int incl = sh[tid];
    if (tid == 1023)
        atomicExch(&pub[blockIdx.x], (unsigned)incl | 0x80000000u);
    if (tid < 64) {
        int s = 0;
        for (int l = tid; l < (int)blockIdx.x; l += 64) {
            unsigned x;
            do { x = atomicAdd(&pub[l], 0u); } while (!(x & 0x80000000u));
            s += (int)(x & 0x7FFFFFFFu);
        }
        #pragma unroll
        for (int off = 32; off > 0; off >>= 1) s += __shfl_xor(s, off, 64);
        if (tid == 0) bpref = s;
    }
    __syncthreads();
    if (i < NCTR) c[i] = bpref + incl - v;        // exclusive prefix
}

// ===========================================================================
// Dispatch 3 — scatter edges into bucket-contiguous pairs[] using LDS ranks.
// pairs[pos] packs src (17 bits) | (dst&127)<<17. nt store (no write-alloc).
// Zero global atomics: rank = LDS atomicAdd on this block's scanned bases.
// ===========================================================================
__global__ __launch_bounds__(256) void scatter_kernel(
    const int* __restrict__ src, const int* __restrict__ dst,
    const int* __restrict__ counters, int* __restrict__ pairs) {
    __shared__ int wk[NBKT];
    int eb = blockIdx.x;
    for (int b = threadIdx.x; b < NBKT; b += 256)
        wk[b] = counters[(size_t)b * NEB + eb];
    __syncthreads();
    int base = eb * EPB;
    #pragma unroll
    for (int k = 0; k < EPB / 256; ++k) {
        int e = base + k * 256 + threadIdx.x;
        if (e < N_EDGES) {
            int s = src[e];
            int d = dst[e];
            int pos = atomicAdd(&wk[d >> BKT_SHIFT], 1);     // LDS atomic
            __builtin_nontemporal_store(s | ((d & (NPB - 1)) << 17),
                                        &pairs[pos]);
        }
    }
}

// ===========================================================================
// Dispatch 4 — per-bucket counting sort IN LDS + fused gather.
// Block j owns bucket j (128 nodes, <=CSR_CAP edges): LDS 128-bin count ->
// scan -> rank -> csr[] in LDS; then 8 waves gather 16 nodes each with the
// proven R8 gather body (csr reads are ds_read; row/cnt/csr_src global
// arrays and the build kernel no longer exist).
// ===========================================================================
__global__ __launch_bounds__(512, 8) void sortgather_kernel(
    const int* __restrict__ counters, const int* __restrict__ pairs,
    const double* __restrict__ h_src, const double* __restrict__ h_dst,
    const _Float16* __restrict__ wvh, float* __restrict__ out) {
    __shared__ int csr[CSR_CAP];
    __shared__ int bin[NPB];
    __shared__ int pref[NPB];
    __shared__ int wk[NPB];
    int j = blockIdx.x;
    int tid = threadIdx.x;

    int start = counters[(size_t)j * NEB];
    int end = (j + 1 < NBKT) ? counters[(size_t)(j + 1) * NEB] : N_EDGES;
    int m = end - start;
    if (m > CSR_CAP) m = CSR_CAP;      // statistically impossible; mem-safety

    if (tid < NPB) bin[tid] = 0;
    __syncthreads();
    for (int k = tid; k < m; k += 512)
        atomicAdd(&bin[(pairs[start + k] >> 17) & (NPB - 1)], 1);
    __syncthreads();
    // exclusive scan of the 128 bins
    if (tid < NPB) pref[tid] = bin[tid];
    __syncthreads();
    for (int off = 1; off < NPB; off <<= 1) {
        int t = 0;
        if (tid < NPB && tid >= off) t = pref[tid - off];
        __syncthreads();
        if (tid < NPB) pref[tid] += t;
        __syncthreads();
    }
    if (tid < NPB) { pref[tid] -= bin[tid]; wk[tid] = pref[tid]; }
    __syncthreads();
    for (int k = tid; k < m; k += 512) {
        int p = pairs[start + k];
        int b = (p >> 17) & (NPB - 1);
        int r = atomicAdd(&wk[b], 1);
        csr[r] = p & 0x1FFFF;
    }
    __syncthreads();

    // ---- fused gather: wave w handles nodes w*16 .. w*16+15 ----
    int wvid = tid >> 6;
    int lane = tid & 63;
    for (int i = 0; i < 16; ++i) {
        int vloc = wvid * 16 + i;
        int vg = (j << BKT_SHIFT) + vloc;
        if (vg >= N_NODES) break;
        int deg = bin[vloc];
        int st = pref[vloc];
        double hd = h_dst[vg];

        if (deg <= 64) {
            int s0 = 0;
            double c0 = 0.0;
            if (lane < deg) {
                s0 = csr[st + lane];
                c0 = h_src[s0] + hd;
            }
            double r = c0;
            if (deg > 32) r += __shfl_xor(r, 32, 64);
            if (deg > 16) r += __shfl_xor(r, 16, 64);
            r += __shfl_xor(r, 8, 64);
            r += __shfl_xor(r, 4, 64);
            r += __shfl_xor(r, 2, 64);
            r += __shfl_xor(r, 1, 64);
            double inv = 1.0 / r;
            float cf0 = (lane < deg) ? (float)(c0 * inv) : 0.f;

            int g8 = lane >> 3;
            int sub8 = lane & 7;
            float ac[8];
            #pragma unroll
            for (int k = 0; k < 8; ++k) ac[k] = 0.f;
            int rounds = (deg + 7) >> 3;
            int jj = 0;
            for (; jj + 2 <= rounds; jj += 2) {
                int l0 = 8 * jj + g8;
                int l1 = l0 + 8;
                int   sA = __shfl(s0, l0, 64);
                float cA = __shfl(cf0, l0, 64);
                int   sB = __shfl(s0, l1, 64);
                float cB = __shfl(cf0, l1, 64);
                half8 vA = ((const half8*)(wvh + (size_t)sA * DIM))[sub8];
                half8 vB = ((const half8*)(wvh + (size_t)sB * DIM))[sub8];
                #pragma unroll
                for (int k = 0; k < 8; ++k) ac[k] += (float)vA[k] * cA;
                #pragma unroll
                for (int k = 0; k < 8; ++k) ac[k] += (float)vB[k] * cB;
            }
            if (jj < rounds) {
                int l0 = 8 * jj + g8;
                int   sA = __shfl(s0, l0, 64);
                float cA = __shfl(cf0, l0, 64);
                half8 vA = ((const half8*)(wvh + (size_t)sA * DIM))[sub8];
                #pragma unroll
                for (int k = 0; k < 8; ++k) ac[k] += (float)vA[k] * cA;
            }
            #pragma unroll
            for (int off = 8; off < 64; off <<= 1) {
                #pragma unroll
                for (int k = 0; k < 8; ++k) ac[k] += __shfl_xor(ac[k], off, 64);
            }
            if (g8 == 0) {
                float4* orow = (float4*)(out + (size_t)vg * DIM + sub8 * 8);
                float4 o0; o0.x = ac[0]; o0.y = ac[1]; o0.z = ac[2]; o0.w = ac[3];
                float4 o1; o1.x = ac[4]; o1.y = ac[5]; o1.z = ac[6]; o1.w = ac[7];
                orow[0] = o0; orow[1] = o1;
            }
        } else {
            double denom = 0.0;
            for (int base = 0; base < deg; base += 64) {
                int mm = deg - base; if (mm > 64) mm = 64;
                double c = 0.0;
                if (lane < mm) {
                    int s = csr[st + base + lane];
                    c = h_src[s] + hd;
                }
                #pragma unroll
                for (int off = 32; off > 0; off >>= 1) c += __shfl_xor(c, off, 64);
                denom += c;
            }
            double inv = 1.0 / denom;
            float acc = 0.f;
            for (int base = 0; base < deg; base += 64) {
                int mm = deg - base; if (mm > 64) mm = 64;
                int s1 = 0; float cf1 = 0.f;
                if (lane < mm) {
                    s1 = csr[st + base + lane];
                    cf1 = (float)((h_src[s1] + hd) * inv);
                }
                for (int q = 0; q < mm; ++q) {
                    int s = lane_bci(s1, q);
                    float cf = lane_bcf(cf1, q);
                    acc += (float)wvh[(size_t)s * DIM + lane] * cf;
                }
            }
            out[(size_t)vg * DIM + lane] = acc;
        }
    }
}

// ---------------------------------------------------------------------------
// Launch — 4 dispatches: fat, scan, scatter, sortgather. No memset.
// ---------------------------------------------------------------------------
extern "C" void kernel_launch(void* const* d_in, const int* in_sizes, int n_in,
                              void* d_out, int out_size, void* d_ws, size_t ws_size,
                              hipStream_t stream) {
    const float* d_u = (const float*)d_in[0];
    const float* p_u = (const float*)d_in[1];
    const float* w_q = (const float*)d_in[2];
    const float* w_k = (const float*)d_in[3];
    const float* w_v = (const float*)d_in[4];
    const float* e1  = (const float*)d_in[5];
    const float* e2  = (const float*)d_in[6];
    const int*   src = (const int*)d_in[7];
    const int*   dst = (const int*)d_in[8];
    float* out = (float*)d_out;

    // Workspace: doubles first (8B aligned), then halfs, then ints.
    double* h_src  = (double*)d_ws;
    double* h_dst  = h_src + N_NODES;
    _Float16* wvh  = (_Float16*)(h_dst + N_NODES);      // N_NODES*DIM halfs
    int* counters  = (int*)(wvh + (size_t)N_NODES * DIM); // NCTR ints
    unsigned int* pub = (unsigned int*)(counters + NCTR); // 256
    int* pairs     = (int*)(pub + 256);                   // N_EDGES ints

    fat_kernel<<<NEB + NW_BLKS, 256, 0, stream>>>(
        dst, d_u, p_u, w_v, w_q, w_k, e1, e2, h_src, h_dst, wvh,
        counters, pub);

    scan_kernel<<<NSB, 1024, 0, stream>>>(counters, pub);

    scatter_kernel<<<NEB, 256, 0, stream>>>(src, dst, counters, pairs);

    sortgather_kernel<<<NBKT, 512, 0, stream>>>(
        counters, pairs, h_src, h_dst, wvh, out);
}

// Round 11
// 221.689 us; speedup vs baseline: 2.5159x; 1.0179x over previous
//
#include <hip/hip_runtime.h>

#define N_NODES 75000
#define N_EDGES 1200000
#define DIM 64

#define EPB 4096                        // edges per hist/scatter block
#define NEB ((N_EDGES + EPB - 1) / EPB) // 293 edge-blocks
#define BKT_SHIFT 6
#define NPB 64                          // nodes per bucket (1<<6)
#define NBKT ((N_NODES + NPB - 1) / NPB) // 1172 buckets
#define NCTR (NBKT * NEB)               // 343,396 counters
#define NSB ((NCTR + 1023) / 1024)      // 336 scan blocks
#define NW_BLKS 1024                    // node_wave blocks inside fat
#define CSR_CAP 1536                    // max edges/bucket (mean 1024, +16 sigma)

typedef _Float16 half8 __attribute__((ext_vector_type(8)));  // 16B = 8 halfs

// Broadcast lane l (wave-uniform) of v to all lanes via v_readlane (VALU).
__device__ __forceinline__ float lane_bcf(float v, int l) {
    return __int_as_float(__builtin_amdgcn_readlane(__float_as_int(v), l));
}
__device__ __forceinline__ int lane_bci(int v, int l) {
    return __builtin_amdgcn_readlane(v, l);
}

// ===========================================================================
// Dispatch 1 — FAT: bucket-histogram (blocks 0..NEB-1) + node_wave (rest).
// LDS-atomic histogram over 1172 coarse buckets (dst>>6) -> per-(bucket,
// edge-block) counter store. Zero global atomics (R2-R7: 24 G/s fabric
// floor). No memset dispatch (counters stored, not accumulated).
// ===========================================================================
__global__ __launch_bounds__(256, 4) void fat_kernel(
    const int* __restrict__ dst,
    const float* __restrict__ d_u, const float* __restrict__ p_u,
    const float* __restrict__ w_v, const float* __restrict__ w_q,
    const float* __restrict__ w_k,
    const float* __restrict__ e1, const float* __restrict__ e2,
    double* __restrict__ h_src, double* __restrict__ h_dst,
    _Float16* __restrict__ wvh,
    int* __restrict__ counters, unsigned int* __restrict__ pub) {

    if (blockIdx.x < NEB) {
        // ---- bucket histogram: 4096 edges -> 1172 LDS bins ----
        __shared__ int lbin[NBKT];
        for (int b = threadIdx.x; b < NBKT; b += 256) lbin[b] = 0;
        if (blockIdx.x == 0) {                       // zero 512 >= NSB entries
            pub[threadIdx.x] = 0u;
            pub[threadIdx.x + 256] = 0u;
        }
        __syncthreads();
        int base = blockIdx.x * EPB;
        #pragma unroll
        for (int k = 0; k < EPB / 256; ++k) {
            int e = base + k * 256 + threadIdx.x;
            if (e < N_EDGES) atomicAdd(&lbin[dst[e] >> BKT_SHIFT], 1);
        }
        __syncthreads();
        for (int b = threadIdx.x; b < NBKT; b += 256)
            counters[(size_t)b * NEB + blockIdx.x] = lbin[b];
        return;
    }

    // ---- node_wave: one wave per node, grid-strided (R8 body, f16 out) ----
    __shared__ double al_sh[DIM];
    __shared__ double bl_sh[DIM];
    int lane = threadIdx.x & 63;
    if (threadIdx.x < DIM) {
        double al = 0.0, bl = 0.0;
        #pragma unroll 8
        for (int j = 0; j < DIM; ++j) {
            al += (double)e1[j] * (double)w_k[j * DIM + threadIdx.x];
            bl += (double)e2[j] * (double)w_q[j * DIM + threadIdx.x];
        }
        al_sh[threadIdx.x] = al;
        bl_sh[threadIdx.x] = bl;
    }
    float w[DIM];
    const float4* wr = (const float4*)(w_v + (size_t)lane * DIM);
    #pragma unroll
    for (int k = 0; k < DIM / 4; ++k) {
        float4 v = wr[k];
        w[4 * k + 0] = v.x; w[4 * k + 1] = v.y;
        w[4 * k + 2] = v.z; w[4 * k + 3] = v.w;
    }
    __syncthreads();
    double al = al_sh[lane];
    double bl = bl_sh[lane];

    int wid = ((blockIdx.x - NEB) * 256 + threadIdx.x) >> 6;
    int nw = NW_BLKS * 4;
    for (int i = wid; i < N_NODES; i += nw) {
        float pl = p_u[(size_t)i * DIM + lane];
        float dl = d_u[(size_t)i * DIM + lane];
        double hs = (double)pl * al;
        #pragma unroll
        for (int off = 32; off > 0; off >>= 1) hs += __shfl_xor(hs, off, 64);
        double hd = (double)dl * bl;
        #pragma unroll
        for (int off = 32; off > 0; off >>= 1) hd += __shfl_xor(hd, off, 64);
        if (lane == 0) { h_src[i] = hs; h_dst[i] = hd; }
        float a0 = 0.f, a1 = 0.f, a2 = 0.f, a3 = 0.f;
        #pragma unroll
        for (int d = 0; d < DIM; d += 4) {
            a0 += w[d + 0] * lane_bcf(pl, d + 0);
            a1 += w[d + 1] * lane_bcf(pl, d + 1);
            a2 += w[d + 2] * lane_bcf(pl, d + 2);
            a3 += w[d + 3] * lane_bcf(pl, d + 3);
        }
        wvh[(size_t)i * DIM + lane] = (_Float16)((a0 + a1) + (a2 + a3));
    }
}

// ===========================================================================
// Dispatch 2 — exclusive scan of counters (bucket-major), in place.
// Lookback publish/spin (R5-proven; 336 blocks all co-resident).
// ===========================================================================
__global__ __launch_bounds__(1024) void scan_kernel(
    int* __restrict__ c, unsigned int* __restrict__ pub) {
    __shared__ int sh[1024];
    __shared__ int bpref;
    int tid = threadIdx.x;
    int i = blockIdx.x * 1024 + tid;
    int v = (i < NCTR) ? c[i] : 0;
    sh[tid] = v;
    __syncthreads();
    for (int off = 1; off < 1024; off <<= 1) {
        int t = (tid >= off) ? sh[tid - off] : 0;
        __syncthreads();
        sh[tid] += t;
        __syncthreads();
    }
    int incl = sh[tid];
    if (tid == 1023)
        atomicExch(&pub[blockIdx.x], (unsigned)incl | 0x80000000u);
    if (tid < 64) {
        int s = 0;
        for (int l = tid; l < (int)blockIdx.x; l += 64) {
            unsigned x;
            do { x = atomicAdd(&pub[l], 0u); } while (!(x & 0x80000000u));
            s += (int)(x & 0x7FFFFFFFu);
        }
        #pragma unroll
        for (int off = 32; off > 0; off >>= 1) s += __shfl_xor(s, off, 64);
        if (tid == 0) bpref = s;
    }
    __syncthreads();
    if (i < NCTR) c[i] = bpref + incl - v;        // exclusive prefix
}

// ===========================================================================
// Dispatch 3 — scatter edges into bucket-contiguous pairs[] using LDS ranks.
// pairs[pos] packs src (17 bits) | (dst&63)<<17. nt store (no write-alloc).
// ===========================================================================
__global__ __launch_bounds__(256) void scatter_kernel(
    const int* __restrict__ src, const int* __restrict__ dst,
    const int* __restrict__ counters, int* __restrict__ pairs) {
    __shared__ int wk[NBKT];
    int eb = blockIdx.x;
    for (int b = threadIdx.x; b < NBKT; b += 256)
        wk[b] = counters[(size_t)b * NEB + eb];
    __syncthreads();
    int base = eb * EPB;
    #pragma unroll
    for (int k = 0; k < EPB / 256; ++k) {
        int e = base + k * 256 + threadIdx.x;
        if (e < N_EDGES) {
            int s = src[e];
            int d = dst[e];
            int pos = atomicAdd(&wk[d >> BKT_SHIFT], 1);     // LDS atomic
            __builtin_nontemporal_store(s | ((d & (NPB - 1)) << 17),
                                        &pairs[pos]);
        }
    }
}

// ===========================================================================
// Dispatch 4 — per-bucket counting sort IN LDS + fused gather.
// R10 counters: occupancy 34.8% (586-block grid = 2.3/CU) bounded the
// outstanding-miss count on the random 128B row fetches (1.3 TB/s achieved).
// R11: NPB 64 -> 1172 blocks x 8 waves = 9376 waves (occupancy-cap bound),
// LDS 6.9KB/block, 8 nodes/wave. Sort: 64-bin LDS count+scan+rank.
// ===========================================================================
__global__ __launch_bounds__(512, 8) void sortgather_kernel(
    const int* __restrict__ counters, const int* __restrict__ pairs,
    const double* __restrict__ h_src, const double* __restrict__ h_dst,
    const _Float16* __restrict__ wvh, float* __restrict__ out) {
    __shared__ int csr[CSR_CAP];
    __shared__ int bin[NPB];
    __shared__ int pref[NPB];
    __shared__ int wk[NPB];
    int j = blockIdx.x;
    int tid = threadIdx.x;

    int start = counters[(size_t)j * NEB];
    int end = (j + 1 < NBKT) ? counters[(size_t)(j + 1) * NEB] : N_EDGES;
    int m = end - start;
    if (m > CSR_CAP) m = CSR_CAP;      // statistically impossible; mem-safety

    if (tid < NPB) bin[tid] = 0;
    __syncthreads();
    for (int k = tid; k < m; k += 512)
        atomicAdd(&bin[(pairs[start + k] >> 17) & (NPB - 1)], 1);
    __syncthreads();
    // exclusive scan of the 64 bins
    if (tid < NPB) pref[tid] = bin[tid];
    __syncthreads();
    for (int off = 1; off < NPB; off <<= 1) {
        int t = 0;
        if (tid < NPB && tid >= off) t = pref[tid - off];
        __syncthreads();
        if (tid < NPB) pref[tid] += t;
        __syncthreads();
    }
    if (tid < NPB) { pref[tid] -= bin[tid]; wk[tid] = pref[tid]; }
    __syncthreads();
    for (int k = tid; k < m; k += 512) {
        int p = pairs[start + k];
        int b = (p >> 17) & (NPB - 1);
        int r = atomicAdd(&wk[b], 1);
        csr[r] = p & 0x1FFFF;
    }
    __syncthreads();

    // ---- fused gather: wave w handles nodes w*8 .. w*8+7 ----
    int wvid = tid >> 6;
    int lane = tid & 63;
    for (int i = 0; i < 8; ++i) {
        int vloc = wvid * 8 + i;
        int vg = (j << BKT_SHIFT) + vloc;
        if (vg >= N_NODES) break;
        int deg = bin[vloc];
        int st = pref[vloc];
        double hd = h_dst[vg];

        if (deg <= 64) {
            int s0 = 0;
            double c0 = 0.0;
            if (lane < deg) {
                s0 = csr[st + lane];
                c0 = h_src[s0] + hd;
            }
            double r = c0;
            if (deg > 32) r += __shfl_xor(r, 32, 64);
            if (deg > 16) r += __shfl_xor(r, 16, 64);
            r += __shfl_xor(r, 8, 64);
            r += __shfl_xor(r, 4, 64);
            r += __shfl_xor(r, 2, 64);
            r += __shfl_xor(r, 1, 64);
            double inv = 1.0 / r;
            float cf0 = (lane < deg) ? (float)(c0 * inv) : 0.f;

            int g8 = lane >> 3;
            int sub8 = lane & 7;
            float ac[8];
            #pragma unroll
            for (int k = 0; k < 8; ++k) ac[k] = 0.f;
            int rounds = (deg + 7) >> 3;
            int jj = 0;
            for (; jj + 2 <= rounds; jj += 2) {
                int l0 = 8 * jj + g8;
                int l1 = l0 + 8;
                int   sA = __shfl(s0, l0, 64);
                float cA = __shfl(cf0, l0, 64);
                int   sB = __shfl(s0, l1, 64);
                float cB = __shfl(cf0, l1, 64);
                half8 vA = ((const half8*)(wvh + (size_t)sA * DIM))[sub8];
                half8 vB = ((const half8*)(wvh + (size_t)sB * DIM))[sub8];
                #pragma unroll
                for (int k = 0; k < 8; ++k) ac[k] += (float)vA[k] * cA;
                #pragma unroll
                for (int k = 0; k < 8; ++k) ac[k] += (float)vB[k] * cB;
            }
            if (jj < rounds) {
                int l0 = 8 * jj + g8;
                int   sA = __shfl(s0, l0, 64);
                float cA = __shfl(cf0, l0, 64);
                half8 vA = ((const half8*)(wvh + (size_t)sA * DIM))[sub8];
                #pragma unroll
                for (int k = 0; k < 8; ++k) ac[k] += (float)vA[k] * cA;
            }
            #pragma unroll
            for (int off = 8; off < 64; off <<= 1) {
                #pragma unroll
                for (int k = 0; k < 8; ++k) ac[k] += __shfl_xor(ac[k], off, 64);
            }
            if (g8 == 0) {
                float4* orow = (float4*)(out + (size_t)vg * DIM + sub8 * 8);
                float4 o0; o0.x = ac[0]; o0.y = ac[1]; o0.z = ac[2]; o0.w = ac[3];
                float4 o1; o1.x = ac[4]; o1.y = ac[5]; o1.z = ac[6]; o1.w = ac[7];
                orow[0] = o0; orow[1] = o1;
            }
        } else {
            double denom = 0.0;
            for (int base = 0; base < deg; base += 64) {
                int mm = deg - base; if (mm > 64) mm = 64;
                double c = 0.0;
                if (lane < mm) {
                    int s = csr[st + base + lane];
                    c = h_src[s] + hd;
                }
                #pragma unroll
                for (int off = 32; off > 0; off >>= 1) c += __shfl_xor(c, off, 64);
                denom += c;
            }
            double inv = 1.0 / denom;
            float acc = 0.f;
            for (int base = 0; base < deg; base += 64) {
                int mm = deg - base; if (mm > 64) mm = 64;
                int s1 = 0; float cf1 = 0.f;
                if (lane < mm) {
                    s1 = csr[st + base + lane];
                    cf1 = (float)((h_src[s1] + hd) * inv);
                }
                for (int q = 0; q < mm; ++q) {
                    int s = lane_bci(s1, q);
                    float cf = lane_bcf(cf1, q);
                    acc += (float)wvh[(size_t)s * DIM + lane] * cf;
                }
            }
            out[(size_t)vg * DIM + lane] = acc;
        }
    }
}

// ---------------------------------------------------------------------------
// Launch — 4 dispatches: fat, scan, scatter, sortgather. No memset.
// ---------------------------------------------------------------------------
extern "C" void kernel_launch(void* const* d_in, const int* in_sizes, int n_in,
                              void* d_out, int out_size, void* d_ws, size_t ws_size,
                              hipStream_t stream) {
    const float* d_u = (const float*)d_in[0];
    const float* p_u = (const float*)d_in[1];
    const float* w_q = (const float*)d_in[2];
    const float* w_k = (const float*)d_in[3];
    const float* w_v = (const float*)d_in[4];
    const float* e1  = (const float*)d_in[5];
    const float* e2  = (const float*)d_in[6];
    const int*   src = (const int*)d_in[7];
    const int*   dst = (const int*)d_in[8];
    float* out = (float*)d_out;

    // Workspace: doubles first (8B aligned), then halfs, then ints.
    double* h_src  = (double*)d_ws;
    double* h_dst  = h_src + N_NODES;
    _Float16* wvh  = (_Float16*)(h_dst + N_NODES);      // N_NODES*DIM halfs
    int* counters  = (int*)(wvh + (size_t)N_NODES * DIM); // NCTR ints
    unsigned int* pub = (unsigned int*)(counters + NCTR); // 512
    int* pairs     = (int*)(pub + 512);                   // N_EDGES ints

    fat_kernel<<<NEB + NW_BLKS, 256, 0, stream>>>(
        dst, d_u, p_u, w_v, w_q, w_k, e1, e2, h_src, h_dst, wvh,
        counters, pub);

    scan_kernel<<<NSB, 1024, 0, stream>>>(counters, pub);

    scatter_kernel<<<NEB, 256, 0, stream>>>(src, dst, counters, pairs);

    sortgather_kernel<<<NBKT, 512, 0, stream>>>(
        counters, pairs, h_src, h_dst, wvh, out);
}